// Round 18
// baseline (192.940 us; speedup 1.0000x reference)
//
#include <hip/hip_runtime.h>
#include <hip/hip_bf16.h>

#define TOPK 30
#define NAT 14
#define EDGE_IN 3152   // 16 PE + 14*14*16 RBF
#define NCHUNK 99      // K chunks of 32 (3168 padded); 99 = 3*33
#define EPB 32         // edges per k_edge block (one wave, M=32)
#define KCW 33         // chunks per K-split
#define WT2N (NCHUNK * 8 * 64)          // 50688 fragment slices
#define WT2_BLOCKS ((WT2N + 255) / 256) // 198

typedef __attribute__((ext_vector_type(8))) short bf16x8;
typedef __attribute__((ext_vector_type(4))) float f32x4;

__device__ __forceinline__ unsigned short f2bf(float f) {
    union { float f; unsigned u; } v; v.f = f;
    unsigned r = v.u + 0x7FFF + ((v.u >> 16) & 1);   // RNE
    return (unsigned short)(r >> 16);
}
__device__ __forceinline__ float bf2f(unsigned short h) {
    union { unsigned u; float f; } v; v.u = ((unsigned)h) << 16;
    return v.f;
}
__device__ __forceinline__ short cvtbf(float f) {    // proven scalar path (116 VGPR in r13)
    __hip_bfloat16 h = __float2bfloat16(f);
    return *reinterpret_cast<short*>(&h);
}

// ---------------- merged: Wt2 pack + Xa prep + node path (one launch) ----------------
__global__ __launch_bounds__(256) void k_misc(const float* __restrict__ X, float* __restrict__ Xa,
                                              const float* __restrict__ EW, unsigned short* __restrict__ Wt2,
                                              const int* __restrict__ S, const float* __restrict__ BB,
                                              const float* __restrict__ NW, const float* __restrict__ nb,
                                              const float* __restrict__ ng, const float* __restrict__ nbe,
                                              float* __restrict__ outV, int N) {
    int b = blockIdx.x;
    if (b < WT2_BLOCKS) {
        int gid = b * 256 + threadIdx.x;
        if (gid >= WT2N) return;
        int ln = gid & 63;
        int kcf = gid >> 6;
        int kc = kcf >> 3, f = kcf & 7;
        int c = f * 16 + (ln & 15);
        int k0 = kc * 32 + (ln >> 4) * 8;
        bf16x8 o;
#pragma unroll
        for (int e = 0; e < 8; e++) {
            int k = k0 + e;
            float v = (k < EDGE_IN) ? EW[(size_t)k * 128 + c] : 0.f;
            o[e] = (short)f2bf(v);
        }
        *reinterpret_cast<bf16x8*>(Wt2 + (size_t)gid * 8) = o;
        return;
    }
    b -= WT2_BLOCKS;
    int prepBlocks = (N + 255) / 256;
    if (b < prepBlocks) {
        int i = b * 256 + threadIdx.x;
        if (i >= N) return;
        const float* xi = X + (size_t)i * NAT * 3;
        float* xo = Xa + (size_t)i * NAT * 3;
        float Nx = xi[0], Ny = xi[1], Nz = xi[2];
        float Ax = xi[3], Ay = xi[4], Az = xi[5];
        float Cx = xi[6], Cy = xi[7], Cz = xi[8];
        float bx = Ax - Nx, by = Ay - Ny, bz = Az - Nz;
        float cx = Cx - Ax, cy = Cy - Ay, cz = Cz - Az;
        float ax = by * cz - bz * cy;
        float ay = bz * cx - bx * cz;
        float az = bx * cy - by * cx;
        float Cbx = -0.58273431f * ax + 0.56802827f * bx - 0.54067466f * cx + Ax;
        float Cby = -0.58273431f * ay + 0.56802827f * by - 0.54067466f * cy + Ay;
        float Cbz = -0.58273431f * az + 0.56802827f * bz - 0.54067466f * cz + Az;
#pragma unroll
        for (int a = 0; a < 4; a++) { xo[a*3] = xi[a*3]; xo[a*3+1] = xi[a*3+1]; xo[a*3+2] = xi[a*3+2]; }
        xo[12] = Cbx; xo[13] = Cby; xo[14] = Cbz;
#pragma unroll
        for (int a = 5; a < 14; a++) { xo[a*3] = xi[a*3]; xo[a*3+1] = xi[a*3+1]; xo[a*3+2] = xi[a*3+2]; }
        return;
    }
    b -= prepBlocks;
    int i = b * 4 + (threadIdx.x >> 6);
    if (i >= N) return;
    int t = threadIdx.x & 63;
    int s = S[i];
    float b0 = BB[i*6], b1 = BB[i*6+1], b2 = BB[i*6+2], b3 = BB[i*6+3], b4 = BB[i*6+4], b5 = BB[i*6+5];
    int t2 = t + 64;
    float x0 = NW[(size_t)s*128 + t] + nb[t]
             + b0*NW[21*128+t] + b1*NW[22*128+t] + b2*NW[23*128+t]
             + b3*NW[24*128+t] + b4*NW[25*128+t] + b5*NW[26*128+t];
    float x1 = NW[(size_t)s*128 + t2] + nb[t2]
             + b0*NW[21*128+t2] + b1*NW[22*128+t2] + b2*NW[23*128+t2]
             + b3*NW[24*128+t2] + b4*NW[25*128+t2] + b5*NW[26*128+t2];
    float sum = x0 + x1;
#pragma unroll
    for (int m = 32; m; m >>= 1) sum += __shfl_xor(sum, m);
    float mean = sum * (1.f / 128.f);
    float d0 = x0 - mean, d1 = x1 - mean;
    float vs = d0*d0 + d1*d1;
#pragma unroll
    for (int m = 32; m; m >>= 1) vs += __shfl_xor(vs, m);
    float inv = 1.f / sqrtf(vs * (1.f / 128.f) + 1e-5f);
    outV[(size_t)i*128 + t]  = d0 * inv * ng[t]  + nbe[t];
    outV[(size_t)i*128 + t2] = d1 * inv * ng[t2] + nbe[t2];
}

// ---------------- exact stable KNN in FLOAT64, two-phase register top-k (proven r13) ----------------
__global__ __launch_bounds__(256) void k_knn(const float* __restrict__ X, const float* __restrict__ mask,
                                             int* __restrict__ Eidx, float* __restrict__ outI, int N) {
    __shared__ double sMax[4];
    __shared__ double sCd[128];
    __shared__ int    sCj[128];
    int i = blockIdx.x, t = threadIdx.x;
    int w = t >> 6, ln = t & 63;
    double mi = (double)mask[i];
    double xx = (double)X[((size_t)i * NAT + 1) * 3 + 0];
    double xy = (double)X[((size_t)i * NAT + 1) * 3 + 1];
    double xz = (double)X[((size_t)i * NAT + 1) * 3 + 2];
    double dv[4], m2v[4];
    double lmax = -1.0;
#pragma unroll
    for (int k = 0; k < 4; k++) {
        int j = w * 256 + ln + 64 * k;
        if (j < N) {
            double dx = xx - (double)X[((size_t)j * NAT + 1) * 3 + 0];
            double dy = xy - (double)X[((size_t)j * NAT + 1) * 3 + 1];
            double dz = xz - (double)X[((size_t)j * NAT + 1) * 3 + 2];
            double sq = ((dx * dx + dy * dy) + dz * dz) + 1e-6;
            double m2 = mi * (double)mask[j];
            double d = m2 * sqrt(sq);
            dv[k] = d; m2v[k] = m2;
            lmax = fmax(lmax, d);
        } else { dv[k] = 1e300; m2v[k] = 1.0; }
    }
#pragma unroll
    for (int m = 32; m; m >>= 1) lmax = fmax(lmax, __shfl_xor(lmax, m));
    if (ln == 0) sMax[w] = lmax;
    __syncthreads();
    double Dmax = fmax(fmax(sMax[0], sMax[1]), fmax(sMax[2], sMax[3]));
#pragma unroll
    for (int k = 0; k < 4; k++) {
        int j = w * 256 + ln + 64 * k;
        if (j < N) dv[k] = dv[k] + 2.0 * (1.0 - m2v[k]) * Dmax;
    }
    for (int s = 0; s < TOPK; s++) {
        double bd = dv[0]; int bj = w * 256 + ln;
        if (dv[1] < bd) { bd = dv[1]; bj = w * 256 + ln + 64; }
        if (dv[2] < bd) { bd = dv[2]; bj = w * 256 + ln + 128; }
        if (dv[3] < bd) { bd = dv[3]; bj = w * 256 + ln + 192; }
#pragma unroll
        for (int m = 32; m; m >>= 1) {
            double od = __shfl_xor(bd, m);
            int oj = __shfl_xor(bj, m);
            if (od < bd || (od == bd && oj < bj)) { bd = od; bj = oj; }
        }
        if (ln == 0) { sCd[w * TOPK + s] = bd; sCj[w * TOPK + s] = bj; }
        int rel = bj - w * 256 - ln;
        if (rel == 0)        dv[0] = 1e300;
        else if (rel == 64)  dv[1] = 1e300;
        else if (rel == 128) dv[2] = 1e300;
        else if (rel == 192) dv[3] = 1e300;
    }
    __syncthreads();
    if (w == 0) {
        double c0 = (ln < 4 * TOPK) ? sCd[ln] : 1e300;
        int    j0 = (ln < 4 * TOPK) ? sCj[ln] : 0x7FFFFFFF;
        int l1 = ln + 64;
        double c1 = (l1 < 4 * TOPK) ? sCd[l1] : 1e300;
        int    j1 = (l1 < 4 * TOPK) ? sCj[l1] : 0x7FFFFFFF;
        for (int s = 0; s < TOPK; s++) {
            double bd = c0; int bj = j0;
            if (c1 < bd || (c1 == bd && j1 < bj)) { bd = c1; bj = j1; }
#pragma unroll
            for (int m = 32; m; m >>= 1) {
                double od = __shfl_xor(bd, m);
                int oj = __shfl_xor(bj, m);
                if (od < bd || (od == bd && oj < bj)) { bd = od; bj = oj; }
            }
            if (ln == 0) {
                Eidx[(size_t)i * TOPK + s] = bj;
                outI[(size_t)i * TOPK + s] = (float)bj;
            }
            if (j0 == bj) c0 = 1e300;
            if (j1 == bj) c1 = 1e300;
        }
    }
}

// ---------------- A-fragment generator: r13-proven scalar path, D passed in ----------------
__device__ __forceinline__ bf16x8 genA(int kb, float dpe, unsigned short du) {
    const float FR[8] = {1.0f, 0.31622776601683794f, 0.1f, 0.03162277660168379f,
                         0.01f, 0.0031622776601683794f, 0.001f, 0.00031622776601683794f};
    const float CS = 0.96089796f;   // 0.8*sqrt(log2 e)
    const float CJ = 1.28119728f;   // (4/3)*CS
    bf16x8 a;
    if (kb < 16) {
#pragma unroll
        for (int jj = 0; jj < 8; jj++) {
            float ang = dpe * FR[jj];
            a[jj] = cvtbf((kb == 0) ? cosf(ang) : sinf(ang));
        }
    } else if (kb >= EDGE_IN) {
#pragma unroll
        for (int jj = 0; jj < 8; jj++) a[jj] = 0;
    } else {
        float D = bf2f(du);
        float bse = (float)((kb - 16) & 15);
        float Dss = D * CS - bse * CJ;
#pragma unroll
        for (int jj = 0; jj < 8; jj++) {
            float u = Dss - (float)jj * CJ;
            a[jj] = cvtbf(__builtin_amdgcn_exp2f(-u * u));
        }
    }
    return a;
}

__device__ __forceinline__ int idxD(int kc, int koff) {
    int idx = 2 * kc + (koff >> 1) - 1;
    return idx < 0 ? 0 : (idx > 195 ? 195 : idx);
}

// ---------------- fused edge features + bf16 MFMA GEMM (K-split-3 partials) ----------------
// 2880 independent one-wave blocks: eb = bid/3 (32 edges), ks = bid%3
// (chunks [33ks,33ks+33)). r13-proven pipeline per block (scalar genA +
// D-register-pipeline). Partial 0 -> f32 P0 (=outE); partials 1,2 -> bf16
// (r15-proven accurate). LN by k_lnred.
__global__ __launch_bounds__(64) void k_edge(const float* __restrict__ Xa, const int* __restrict__ Eidx,
                                             const unsigned short* __restrict__ Wt2,
                                             float* __restrict__ P0, unsigned short* __restrict__ P1h,
                                             unsigned short* __restrict__ P2h, int N) {
    __shared__ unsigned short sDh[EPB * 200];            // bf16 D table, 12.8 KB
    __shared__ float sDpe[EPB];
    const int NE = N * TOPK;
    int t = threadIdx.x;                 // 0..63, one wave
    int eb = blockIdx.x / 3, ks = blockIdx.x - eb * 3;
    int geBase = eb * EPB;
    int kc0 = ks * KCW;
    int kcEnd = kc0 + KCW;

    const unsigned short* gB = Wt2 + (size_t)t * 8;      // lane fragment base

    // prologue: issue first B chunk so it flies under the D-table build
    bf16x8 bA[8], bB[8];
#pragma unroll
    for (int f = 0; f < 8; f++)
        bA[f] = *reinterpret_cast<const bf16x8*>(gB + ((size_t)kc0 * 8 + f) * 512);

    // D-table build: 2 threads per edge, 98 pair-distances each
    {
        int le = t >> 1, q = t & 1;
        int ge = geBase + le; if (ge >= NE) ge = NE - 1;
        int i = ge / TOPK;
        int j = Eidx[ge];
        if (q == 0) sDpe[le] = (float)j - (float)i;
        const float* Xi = Xa + (size_t)i * NAT * 3;
        const float* Xj = Xa + (size_t)j * NAT * 3;
        for (int p = q; p < 196; p += 2) {
            int a = p / 14, b = p - 14 * a;
            float dx = Xi[a*3+0] - Xj[b*3+0];
            float dy = Xi[a*3+1] - Xj[b*3+1];
            float dz = Xi[a*3+2] - Xj[b*3+2];
            sDh[le * 200 + p] = f2bf(sqrtf(dx*dx + dy*dy + dz*dz + 1e-6f));
        }
    }
    asm volatile("s_waitcnt lgkmcnt(0)" ::: "memory");   // single wave: our ds_writes done

    int lrow = t & 15, koff = t >> 4;
    const unsigned short* sDrow0 = sDh + (size_t)lrow * 200;
    const unsigned short* sDrow1 = sDh + (size_t)(lrow + 16) * 200;
    float dpe0 = sDpe[lrow];
    float dpe1 = sDpe[lrow + 16];

    f32x4 acc0[8], acc1[8];
#pragma unroll
    for (int f = 0; f < 8; f++) { acc0[f] = (f32x4){0.f,0.f,0.f,0.f}; acc1[f] = (f32x4){0.f,0.f,0.f,0.f}; }

    // D pipeline prologue: chunks kc0, kc0+1, kc0+2
    int i0 = idxD(kc0, koff), i1 = idxD(kc0 + 1, koff), i2 = idxD(kc0 + 2, koff);
    unsigned short p0a = sDrow0[i0], p0b = sDrow1[i0];
    unsigned short p1a = sDrow0[i1], p1b = sDrow1[i1];
    unsigned short p2a = sDrow0[i2], p2b = sDrow1[i2];

    bf16x8 a0c = genA(kc0 * 32 + koff * 8, dpe0, p0a);
    bf16x8 a1c = genA(kc0 * 32 + koff * 8, dpe1, p0b);

    for (int kc = kc0; kc < kcEnd; kc += 2) {
        int i3 = idxD(kc + 3, koff);
        unsigned short p3a = sDrow0[i3], p3b = sDrow1[i3];
        bf16x8 a0n, a1n;
        if (kc + 1 < kcEnd) {
#pragma unroll
            for (int f = 0; f < 8; f++)
                bB[f] = *reinterpret_cast<const bf16x8*>(gB + ((size_t)(kc + 1) * 8 + f) * 512);
            int kb = (kc + 1) * 32 + koff * 8;
            a0n = genA(kb, dpe0, p1a);
            a1n = genA(kb, dpe1, p1b);
        }
#pragma unroll
        for (int f = 0; f < 8; f++) {
            acc0[f] = __builtin_amdgcn_mfma_f32_16x16x32_bf16(a0c, bA[f], acc0[f], 0, 0, 0);
            acc1[f] = __builtin_amdgcn_mfma_f32_16x16x32_bf16(a1c, bA[f], acc1[f], 0, 0, 0);
        }
        int i4 = idxD(kc + 4, koff);
        unsigned short p4a = sDrow0[i4], p4b = sDrow1[i4];
        if (kc + 2 < kcEnd) {
#pragma unroll
            for (int f = 0; f < 8; f++)
                bA[f] = *reinterpret_cast<const bf16x8*>(gB + ((size_t)(kc + 2) * 8 + f) * 512);
            int kb = (kc + 2) * 32 + koff * 8;
            a0c = genA(kb, dpe0, p2a);
            a1c = genA(kb, dpe1, p2b);
        }
        if (kc + 1 < kcEnd) {
#pragma unroll
            for (int f = 0; f < 8; f++) {
                acc0[f] = __builtin_amdgcn_mfma_f32_16x16x32_bf16(a0n, bB[f], acc0[f], 0, 0, 0);
                acc1[f] = __builtin_amdgcn_mfma_f32_16x16x32_bf16(a1n, bB[f], acc1[f], 0, 0, 0);
            }
        }
        p1a = p3a; p1b = p3b;
        p2a = p4a; p2b = p4b;
    }

    // write raw partial; ks=0 -> f32, ks=1/2 -> bf16 (r15-proven accurate)
    if (ks == 0) {
#pragma unroll
        for (int g2 = 0; g2 < 2; g2++)
#pragma unroll
            for (int r = 0; r < 4; r++) {
                int row = geBase + g2 * 16 + koff * 4 + r;
                if (row < NE) {
                    float* po = P0 + (size_t)row * 128 + lrow;
#pragma unroll
                    for (int f = 0; f < 8; f++) po[f * 16] = (g2 ? acc1[f][r] : acc0[f][r]);
                }
            }
    } else {
        unsigned short* Ph = (ks == 1) ? P1h : P2h;
#pragma unroll
        for (int g2 = 0; g2 < 2; g2++)
#pragma unroll
            for (int r = 0; r < 4; r++) {
                int row = geBase + g2 * 16 + koff * 4 + r;
                if (row < NE) {
                    unsigned short* po = Ph + (size_t)row * 128 + lrow;
#pragma unroll
                    for (int f = 0; f < 8; f++) po[f * 16] = f2bf(g2 ? acc1[f][r] : acc0[f][r]);
                }
            }
    }
}

// ---------------- reduce partials + bias + LN (one wave per row, r15-proven) ----------------
__global__ __launch_bounds__(64) void k_lnred(const float* __restrict__ P0, const unsigned short* __restrict__ P1h,
                                              const unsigned short* __restrict__ P2h,
                                              const float* __restrict__ eb, const float* __restrict__ gg,
                                              const float* __restrict__ bb, float* __restrict__ outE) {
    int row = blockIdx.x, t = threadIdx.x;
    int c0 = t, c1 = t + 64;
    size_t base = (size_t)row * 128;
    float x0 = P0[base + c0] + bf2f(P1h[base + c0]) + bf2f(P2h[base + c0]) + eb[c0];
    float x1 = P0[base + c1] + bf2f(P1h[base + c1]) + bf2f(P2h[base + c1]) + eb[c1];
    float sum = x0 + x1;
#pragma unroll
    for (int m = 32; m; m >>= 1) sum += __shfl_xor(sum, m);
    float mean = sum * (1.f / 128.f);
    float d0 = x0 - mean, d1 = x1 - mean;
    float vs = d0*d0 + d1*d1;
#pragma unroll
    for (int m = 32; m; m >>= 1) vs += __shfl_xor(vs, m);
    float inv = 1.f / sqrtf(vs * (1.f / 128.f) + 1e-5f);
    outE[base + c0] = d0 * inv * gg[c0] + bb[c0];
    outE[base + c1] = d1 * inv * gg[c1] + bb[c1];
}

extern "C" void kernel_launch(void* const* d_in, const int* in_sizes, int n_in,
                              void* d_out, int out_size, void* d_ws, size_t ws_size,
                              hipStream_t stream) {
    const float* X       = (const float*)d_in[0];
    const int*   S       = (const int*)d_in[1];
    const float* BB      = (const float*)d_in[2];
    const float* mask    = (const float*)d_in[3];
    const float* node_w  = (const float*)d_in[4];
    const float* node_b  = (const float*)d_in[5];
    const float* node_g  = (const float*)d_in[6];
    const float* node_lb = (const float*)d_in[7];
    const float* edge_w  = (const float*)d_in[8];
    const float* edge_b  = (const float*)d_in[9];
    const float* edge_g  = (const float*)d_in[10];
    const float* edge_lb = (const float*)d_in[11];
    int N  = in_sizes[1];       // 1024
    int NE = N * TOPK;

    float* out  = (float*)d_out;
    float* outV = out;                                  // N*128 f32
    float* outE = out + (size_t)N * 128;                // NE*128 f32  (doubles as P0)
    float* outI = outE + (size_t)NE * 128;              // NE f32

    char* ws = (char*)d_ws;
    int* Eidx = (int*)ws;
    size_t off = ((size_t)NE * 4 + 255) & ~(size_t)255;
    float* Xa = (float*)(ws + off);
    off += (((size_t)N * NAT * 3 * 4) + 255) & ~(size_t)255;
    unsigned short* Wt2 = (unsigned short*)(ws + off);  // WT2N*8 bf16 = 811008 B
    off += ((size_t)WT2N * 8 * 2 + 255) & ~(size_t)255;
    unsigned short* P1h = (unsigned short*)(ws + off);  // NE*128 bf16 = 7.86 MB
    off += ((size_t)NE * 128 * 2 + 255) & ~(size_t)255;
    unsigned short* P2h = (unsigned short*)(ws + off);  // NE*128 bf16 = 7.86 MB

    int prepBlocks = (N + 255) / 256;
    int nodeBlocks = (N + 3) / 4;
    int miscBlocks = WT2_BLOCKS + prepBlocks + nodeBlocks;
    k_misc<<<dim3(miscBlocks), dim3(256), 0, stream>>>(X, Xa, edge_w, Wt2,
                                                       S, BB, node_w, node_b, node_g, node_lb, outV, N);
    k_knn<<<dim3(N), dim3(256), 0, stream>>>(X, mask, Eidx, outI, N);
    k_edge<<<dim3(((NE + EPB - 1) / EPB) * 3), dim3(64), 0, stream>>>(Xa, Eidx, Wt2, outE, P1h, P2h, N);
    k_lnred<<<dim3(NE), dim3(64), 0, stream>>>(outE, P1h, P2h, edge_b, edge_g, edge_lb, outE);
}

// Round 19
// 187.811 us; speedup vs baseline: 1.0273x; 1.0273x over previous
//
#include <hip/hip_runtime.h>
#include <hip/hip_bf16.h>

#define TOPK 30
#define NAT 14
#define EDGE_IN 3152   // 16 PE + 14*14*16 RBF
#define NCHUNK 99      // K chunks of 32 (3168 padded); 99 = 3*33
#define EPB 32         // edges per k_edge block (one wave, M=32)
#define KCW 33         // chunks per K-split (split-3)
#define WT2N (NCHUNK * 8 * 64)          // 50688 fragment slices
#define WT2_BLOCKS ((WT2N + 255) / 256) // 198

typedef __attribute__((ext_vector_type(8))) short bf16x8;
typedef __attribute__((ext_vector_type(4))) float f32x4;

__device__ __forceinline__ unsigned short f2bf(float f) {
    union { float f; unsigned u; } v; v.f = f;
    unsigned r = v.u + 0x7FFF + ((v.u >> 16) & 1);   // RNE
    return (unsigned short)(r >> 16);
}
__device__ __forceinline__ float bf2f(unsigned short h) {
    union { unsigned u; float f; } v; v.u = ((unsigned)h) << 16;
    return v.f;
}
__device__ __forceinline__ short cvtbf(float f) {    // proven scalar path (116 VGPR in r13)
    __hip_bfloat16 h = __float2bfloat16(f);
    return *reinterpret_cast<short*>(&h);
}

// ---------------- merged front: KNN blocks [0,N) + misc (Wt2/prep/node) after ----------------
__global__ __launch_bounds__(256) void k_front(const float* __restrict__ X, const float* __restrict__ mask,
                                               int* __restrict__ Eidx, float* __restrict__ outI,
                                               float* __restrict__ Xa,
                                               const float* __restrict__ EW, unsigned short* __restrict__ Wt2,
                                               const int* __restrict__ S, const float* __restrict__ BB,
                                               const float* __restrict__ NW, const float* __restrict__ nb,
                                               const float* __restrict__ ng, const float* __restrict__ nbe,
                                               float* __restrict__ outV, int N) {
    __shared__ double sMax[4];
    __shared__ double sCd[128];
    __shared__ int    sCj[128];
    int b = blockIdx.x;
    if (b < N) {
        // ---- exact stable KNN in f64, two-phase register top-k (proven r13) ----
        int i = b, t = threadIdx.x;
        int w = t >> 6, ln = t & 63;
        double mi = (double)mask[i];
        double xx = (double)X[((size_t)i * NAT + 1) * 3 + 0];
        double xy = (double)X[((size_t)i * NAT + 1) * 3 + 1];
        double xz = (double)X[((size_t)i * NAT + 1) * 3 + 2];
        double dv[4], m2v[4];
        double lmax = -1.0;
#pragma unroll
        for (int k = 0; k < 4; k++) {
            int j = w * 256 + ln + 64 * k;
            if (j < N) {
                double dx = xx - (double)X[((size_t)j * NAT + 1) * 3 + 0];
                double dy = xy - (double)X[((size_t)j * NAT + 1) * 3 + 1];
                double dz = xz - (double)X[((size_t)j * NAT + 1) * 3 + 2];
                double sq = ((dx * dx + dy * dy) + dz * dz) + 1e-6;
                double m2 = mi * (double)mask[j];
                double d = m2 * sqrt(sq);
                dv[k] = d; m2v[k] = m2;
                lmax = fmax(lmax, d);
            } else { dv[k] = 1e300; m2v[k] = 1.0; }
        }
#pragma unroll
        for (int m = 32; m; m >>= 1) lmax = fmax(lmax, __shfl_xor(lmax, m));
        if (ln == 0) sMax[w] = lmax;
        __syncthreads();
        double Dmax = fmax(fmax(sMax[0], sMax[1]), fmax(sMax[2], sMax[3]));
#pragma unroll
        for (int k = 0; k < 4; k++) {
            int j = w * 256 + ln + 64 * k;
            if (j < N) dv[k] = dv[k] + 2.0 * (1.0 - m2v[k]) * Dmax;
        }
        for (int s = 0; s < TOPK; s++) {
            double bd = dv[0]; int bj = w * 256 + ln;
            if (dv[1] < bd) { bd = dv[1]; bj = w * 256 + ln + 64; }
            if (dv[2] < bd) { bd = dv[2]; bj = w * 256 + ln + 128; }
            if (dv[3] < bd) { bd = dv[3]; bj = w * 256 + ln + 192; }
#pragma unroll
            for (int m = 32; m; m >>= 1) {
                double od = __shfl_xor(bd, m);
                int oj = __shfl_xor(bj, m);
                if (od < bd || (od == bd && oj < bj)) { bd = od; bj = oj; }
            }
            if (ln == 0) { sCd[w * TOPK + s] = bd; sCj[w * TOPK + s] = bj; }
            int rel = bj - w * 256 - ln;
            if (rel == 0)        dv[0] = 1e300;
            else if (rel == 64)  dv[1] = 1e300;
            else if (rel == 128) dv[2] = 1e300;
            else if (rel == 192) dv[3] = 1e300;
        }
        __syncthreads();
        if (w == 0) {
            double c0 = (ln < 4 * TOPK) ? sCd[ln] : 1e300;
            int    j0 = (ln < 4 * TOPK) ? sCj[ln] : 0x7FFFFFFF;
            int l1 = ln + 64;
            double c1 = (l1 < 4 * TOPK) ? sCd[l1] : 1e300;
            int    j1 = (l1 < 4 * TOPK) ? sCj[l1] : 0x7FFFFFFF;
            for (int s = 0; s < TOPK; s++) {
                double bd = c0; int bj = j0;
                if (c1 < bd || (c1 == bd && j1 < bj)) { bd = c1; bj = j1; }
#pragma unroll
                for (int m = 32; m; m >>= 1) {
                    double od = __shfl_xor(bd, m);
                    int oj = __shfl_xor(bj, m);
                    if (od < bd || (od == bd && oj < bj)) { bd = od; bj = oj; }
                }
                if (ln == 0) {
                    Eidx[(size_t)i * TOPK + s] = bj;
                    outI[(size_t)i * TOPK + s] = (float)bj;
                }
                if (j0 == bj) c0 = 1e300;
                if (j1 == bj) c1 = 1e300;
            }
        }
        return;
    }
    b -= N;
    if (b < WT2_BLOCKS) {
        int gid = b * 256 + threadIdx.x;
        if (gid >= WT2N) return;
        int ln = gid & 63;
        int kcf = gid >> 6;
        int kc = kcf >> 3, f = kcf & 7;
        int c = f * 16 + (ln & 15);
        int k0 = kc * 32 + (ln >> 4) * 8;
        bf16x8 o;
#pragma unroll
        for (int e = 0; e < 8; e++) {
            int k = k0 + e;
            float v = (k < EDGE_IN) ? EW[(size_t)k * 128 + c] : 0.f;
            o[e] = (short)f2bf(v);
        }
        *reinterpret_cast<bf16x8*>(Wt2 + (size_t)gid * 8) = o;
        return;
    }
    b -= WT2_BLOCKS;
    int prepBlocks = (N + 255) / 256;
    if (b < prepBlocks) {
        int i = b * 256 + threadIdx.x;
        if (i >= N) return;
        const float* xi = X + (size_t)i * NAT * 3;
        float* xo = Xa + (size_t)i * NAT * 3;
        float Nx = xi[0], Ny = xi[1], Nz = xi[2];
        float Ax = xi[3], Ay = xi[4], Az = xi[5];
        float Cx = xi[6], Cy = xi[7], Cz = xi[8];
        float bx = Ax - Nx, by = Ay - Ny, bz = Az - Nz;
        float cx = Cx - Ax, cy = Cy - Ay, cz = Cz - Az;
        float ax = by * cz - bz * cy;
        float ay = bz * cx - bx * cz;
        float az = bx * cy - by * cx;
        float Cbx = -0.58273431f * ax + 0.56802827f * bx - 0.54067466f * cx + Ax;
        float Cby = -0.58273431f * ay + 0.56802827f * by - 0.54067466f * cy + Ay;
        float Cbz = -0.58273431f * az + 0.56802827f * bz - 0.54067466f * cz + Az;
#pragma unroll
        for (int a = 0; a < 4; a++) { xo[a*3] = xi[a*3]; xo[a*3+1] = xi[a*3+1]; xo[a*3+2] = xi[a*3+2]; }
        xo[12] = Cbx; xo[13] = Cby; xo[14] = Cbz;
#pragma unroll
        for (int a = 5; a < 14; a++) { xo[a*3] = xi[a*3]; xo[a*3+1] = xi[a*3+1]; xo[a*3+2] = xi[a*3+2]; }
        return;
    }
    b -= prepBlocks;
    int i = b * 4 + (threadIdx.x >> 6);
    if (i >= N) return;
    int t = threadIdx.x & 63;
    int s = S[i];
    float b0 = BB[i*6], b1 = BB[i*6+1], b2 = BB[i*6+2], b3 = BB[i*6+3], b4 = BB[i*6+4], b5 = BB[i*6+5];
    int t2 = t + 64;
    float x0 = NW[(size_t)s*128 + t] + nb[t]
             + b0*NW[21*128+t] + b1*NW[22*128+t] + b2*NW[23*128+t]
             + b3*NW[24*128+t] + b4*NW[25*128+t] + b5*NW[26*128+t];
    float x1 = NW[(size_t)s*128 + t2] + nb[t2]
             + b0*NW[21*128+t2] + b1*NW[22*128+t2] + b2*NW[23*128+t2]
             + b3*NW[24*128+t2] + b4*NW[25*128+t2] + b5*NW[26*128+t2];
    float sum = x0 + x1;
#pragma unroll
    for (int m = 32; m; m >>= 1) sum += __shfl_xor(sum, m);
    float mean = sum * (1.f / 128.f);
    float d0 = x0 - mean, d1 = x1 - mean;
    float vs = d0*d0 + d1*d1;
#pragma unroll
    for (int m = 32; m; m >>= 1) vs += __shfl_xor(vs, m);
    float inv = 1.f / sqrtf(vs * (1.f / 128.f) + 1e-5f);
    outV[(size_t)i*128 + t]  = d0 * inv * ng[t]  + nbe[t];
    outV[(size_t)i*128 + t2] = d1 * inv * ng[t2] + nbe[t2];
}

// ---------------- A-fragment generator: r13-proven scalar path, D passed in ----------------
__device__ __forceinline__ bf16x8 genA(int kb, float dpe, unsigned short du) {
    const float FR[8] = {1.0f, 0.31622776601683794f, 0.1f, 0.03162277660168379f,
                         0.01f, 0.0031622776601683794f, 0.001f, 0.00031622776601683794f};
    const float CS = 0.96089796f;   // 0.8*sqrt(log2 e)
    const float CJ = 1.28119728f;   // (4/3)*CS
    bf16x8 a;
    if (kb < 16) {
#pragma unroll
        for (int jj = 0; jj < 8; jj++) {
            float ang = dpe * FR[jj];
            a[jj] = cvtbf((kb == 0) ? cosf(ang) : sinf(ang));
        }
    } else if (kb >= EDGE_IN) {
#pragma unroll
        for (int jj = 0; jj < 8; jj++) a[jj] = 0;
    } else {
        float D = bf2f(du);
        float bse = (float)((kb - 16) & 15);
        float Dss = D * CS - bse * CJ;
#pragma unroll
        for (int jj = 0; jj < 8; jj++) {
            float u = Dss - (float)jj * CJ;
            a[jj] = cvtbf(__builtin_amdgcn_exp2f(-u * u));
        }
    }
    return a;
}

__device__ __forceinline__ int idxD(int kc, int koff) {
    int idx = 2 * kc + (koff >> 1) - 1;
    return idx < 0 ? 0 : (idx > 195 ? 195 : idx);
}

// ================== shared k_edge body (D build + K-loop) ==================
// Computes acc0/acc1 for chunks [kc0,kcEnd) of edge-block geBase. r13-proven.
__device__ __forceinline__ void edge_body(const float* __restrict__ Xa, const int* __restrict__ Eidx,
                                          const unsigned short* __restrict__ Wt2,
                                          unsigned short* sDh, float* sDpe,
                                          int t, int geBase, int kc0, int kcEnd, int NE,
                                          f32x4 acc0[8], f32x4 acc1[8]) {
    const unsigned short* gB = Wt2 + (size_t)t * 8;

    bf16x8 bA[8], bB[8];
#pragma unroll
    for (int f = 0; f < 8; f++)
        bA[f] = *reinterpret_cast<const bf16x8*>(gB + ((size_t)kc0 * 8 + f) * 512);

    {
        int le = t >> 1, q = t & 1;
        int ge = geBase + le; if (ge >= NE) ge = NE - 1;
        int i = ge / TOPK;
        int j = Eidx[ge];
        if (q == 0) sDpe[le] = (float)j - (float)i;
        const float* Xi = Xa + (size_t)i * NAT * 3;
        const float* Xj = Xa + (size_t)j * NAT * 3;
        for (int p = q; p < 196; p += 2) {
            int a = p / 14, b = p - 14 * a;
            float dx = Xi[a*3+0] - Xj[b*3+0];
            float dy = Xi[a*3+1] - Xj[b*3+1];
            float dz = Xi[a*3+2] - Xj[b*3+2];
            sDh[le * 200 + p] = f2bf(sqrtf(dx*dx + dy*dy + dz*dz + 1e-6f));
        }
    }
    asm volatile("s_waitcnt lgkmcnt(0)" ::: "memory");   // single wave: our ds_writes done

    int lrow = t & 15, koff = t >> 4;
    const unsigned short* sDrow0 = sDh + (size_t)lrow * 200;
    const unsigned short* sDrow1 = sDh + (size_t)(lrow + 16) * 200;
    float dpe0 = sDpe[lrow];
    float dpe1 = sDpe[lrow + 16];

#pragma unroll
    for (int f = 0; f < 8; f++) { acc0[f] = (f32x4){0.f,0.f,0.f,0.f}; acc1[f] = (f32x4){0.f,0.f,0.f,0.f}; }

    int i0 = idxD(kc0, koff), i1 = idxD(kc0 + 1, koff), i2 = idxD(kc0 + 2, koff);
    unsigned short p0a = sDrow0[i0], p0b = sDrow1[i0];
    unsigned short p1a = sDrow0[i1], p1b = sDrow1[i1];
    unsigned short p2a = sDrow0[i2], p2b = sDrow1[i2];

    bf16x8 a0c = genA(kc0 * 32 + koff * 8, dpe0, p0a);
    bf16x8 a1c = genA(kc0 * 32 + koff * 8, dpe1, p0b);

    for (int kc = kc0; kc < kcEnd; kc += 2) {
        int i3 = idxD(kc + 3, koff);
        unsigned short p3a = sDrow0[i3], p3b = sDrow1[i3];
        bf16x8 a0n, a1n;
        if (kc + 1 < kcEnd) {
#pragma unroll
            for (int f = 0; f < 8; f++)
                bB[f] = *reinterpret_cast<const bf16x8*>(gB + ((size_t)(kc + 1) * 8 + f) * 512);
            int kb = (kc + 1) * 32 + koff * 8;
            a0n = genA(kb, dpe0, p1a);
            a1n = genA(kb, dpe1, p1b);
        }
#pragma unroll
        for (int f = 0; f < 8; f++) {
            acc0[f] = __builtin_amdgcn_mfma_f32_16x16x32_bf16(a0c, bA[f], acc0[f], 0, 0, 0);
            acc1[f] = __builtin_amdgcn_mfma_f32_16x16x32_bf16(a1c, bA[f], acc1[f], 0, 0, 0);
        }
        int i4 = idxD(kc + 4, koff);
        unsigned short p4a = sDrow0[i4], p4b = sDrow1[i4];
        if (kc + 2 < kcEnd) {
#pragma unroll
            for (int f = 0; f < 8; f++)
                bA[f] = *reinterpret_cast<const bf16x8*>(gB + ((size_t)(kc + 2) * 8 + f) * 512);
            int kb = (kc + 2) * 32 + koff * 8;
            a0c = genA(kb, dpe0, p2a);
            a1c = genA(kb, dpe1, p2b);
        }
        if (kc + 1 < kcEnd) {
#pragma unroll
            for (int f = 0; f < 8; f++) {
                acc0[f] = __builtin_amdgcn_mfma_f32_16x16x32_bf16(a0n, bB[f], acc0[f], 0, 0, 0);
                acc1[f] = __builtin_amdgcn_mfma_f32_16x16x32_bf16(a1n, bB[f], acc1[f], 0, 0, 0);
            }
        }
        p1a = p3a; p1b = p3b;
        p2a = p4a; p2b = p4b;
    }
}

// ---------------- k_edge3: K-split-3, UNIFORM f32 partial epilogue ----------------
__global__ __launch_bounds__(64) void k_edge3(const float* __restrict__ Xa, const int* __restrict__ Eidx,
                                              const unsigned short* __restrict__ Wt2,
                                              float* __restrict__ P0, float* __restrict__ P1,
                                              float* __restrict__ P2, int N) {
    __shared__ unsigned short sDh[EPB * 200];
    __shared__ float sDpe[EPB];
    const int NE = N * TOPK;
    int t = threadIdx.x;
    int eb = blockIdx.x / 3, ks = blockIdx.x - eb * 3;
    int geBase = eb * EPB;
    int kc0 = ks * KCW;
    float* Pdst = (ks == 0) ? P0 : ((ks == 1) ? P1 : P2);   // uniform store body below

    f32x4 acc0[8], acc1[8];
    edge_body(Xa, Eidx, Wt2, sDh, sDpe, t, geBase, kc0, kc0 + KCW, NE, acc0, acc1);

    int lrow = t & 15, koff = t >> 4;
#pragma unroll
    for (int g2 = 0; g2 < 2; g2++)
#pragma unroll
        for (int r = 0; r < 4; r++) {
            int row = geBase + g2 * 16 + koff * 4 + r;
            if (row < NE) {
                float* po = Pdst + (size_t)row * 128 + lrow;
#pragma unroll
                for (int f = 0; f < 8; f++) po[f * 16] = (g2 ? acc1[f][r] : acc0[f][r]);
            }
        }
}

// ---------------- k_edge1: r13-verbatim single-pass with fused LN (fallback) ----------------
__global__ __launch_bounds__(64) void k_edge1(const float* __restrict__ Xa, const int* __restrict__ Eidx,
                                              const unsigned short* __restrict__ Wt2,
                                              const float* __restrict__ ebias, const float* __restrict__ egain,
                                              const float* __restrict__ ebeta,
                                              float* __restrict__ outE, int N) {
    __shared__ unsigned short sDh[EPB * 200];
    __shared__ float sDpe[EPB];
    const int NE = N * TOPK;
    int t = threadIdx.x;
    int geBase = blockIdx.x * EPB;

    f32x4 acc0[8], acc1[8];
    edge_body(Xa, Eidx, Wt2, sDh, sDpe, t, geBase, 0, NCHUNK, NE, acc0, acc1);

    int lrow = t & 15, koff = t >> 4;
    float gg[8], bb2[8], eb[8];
#pragma unroll
    for (int f = 0; f < 8; f++) { int c = f * 16 + lrow; gg[f] = egain[c]; bb2[f] = ebeta[c]; eb[f] = ebias[c]; }
#pragma unroll
    for (int g2 = 0; g2 < 2; g2++) {
#pragma unroll
        for (int r = 0; r < 4; r++) {
            float x[8], sum = 0.f;
#pragma unroll
            for (int f = 0; f < 8; f++) {
                float v = (g2 ? acc1[f][r] : acc0[f][r]) + eb[f];
                x[f] = v; sum += v;
            }
#pragma unroll
            for (int m = 1; m < 16; m <<= 1) sum += __shfl_xor(sum, m);
            float mean = sum * (1.f / 128.f);
            float vs = 0.f;
#pragma unroll
            for (int f = 0; f < 8; f++) { float d2 = x[f] - mean; vs += d2 * d2; }
#pragma unroll
            for (int m = 1; m < 16; m <<= 1) vs += __shfl_xor(vs, m);
            float inv = 1.f / sqrtf(vs * (1.f / 128.f) + 1e-5f);
            int row = geBase + g2 * 16 + koff * 4 + r;
            if (row < NE) {
                float* po = outE + (size_t)row * 128 + lrow;
#pragma unroll
                for (int f = 0; f < 8; f++) po[f * 16] = (x[f] - mean) * inv * gg[f] + bb2[f];
            }
        }
    }
}

// ---------------- reduce 3 f32 partials + bias + LN (one wave per row) ----------------
__global__ __launch_bounds__(64) void k_lnred3(const float* __restrict__ P0, const float* __restrict__ P1,
                                               const float* __restrict__ P2,
                                               const float* __restrict__ eb, const float* __restrict__ gg,
                                               const float* __restrict__ bb, float* __restrict__ outE) {
    int row = blockIdx.x, t = threadIdx.x;
    int c0 = t, c1 = t + 64;
    size_t base = (size_t)row * 128;
    float x0 = P0[base + c0] + P1[base + c0] + P2[base + c0] + eb[c0];
    float x1 = P0[base + c1] + P1[base + c1] + P2[base + c1] + eb[c1];
    float sum = x0 + x1;
#pragma unroll
    for (int m = 32; m; m >>= 1) sum += __shfl_xor(sum, m);
    float mean = sum * (1.f / 128.f);
    float d0 = x0 - mean, d1 = x1 - mean;
    float vs = d0*d0 + d1*d1;
#pragma unroll
    for (int m = 32; m; m >>= 1) vs += __shfl_xor(vs, m);
    float inv = 1.f / sqrtf(vs * (1.f / 128.f) + 1e-5f);
    outE[base + c0] = d0 * inv * gg[c0] + bb[c0];
    outE[base + c1] = d1 * inv * gg[c1] + bb[c1];
}

extern "C" void kernel_launch(void* const* d_in, const int* in_sizes, int n_in,
                              void* d_out, int out_size, void* d_ws, size_t ws_size,
                              hipStream_t stream) {
    const float* X       = (const float*)d_in[0];
    const int*   S       = (const int*)d_in[1];
    const float* BB      = (const float*)d_in[2];
    const float* mask    = (const float*)d_in[3];
    const float* node_w  = (const float*)d_in[4];
    const float* node_b  = (const float*)d_in[5];
    const float* node_g  = (const float*)d_in[6];
    const float* node_lb = (const float*)d_in[7];
    const float* edge_w  = (const float*)d_in[8];
    const float* edge_b  = (const float*)d_in[9];
    const float* edge_g  = (const float*)d_in[10];
    const float* edge_lb = (const float*)d_in[11];
    int N  = in_sizes[1];       // 1024
    int NE = N * TOPK;

    float* out  = (float*)d_out;
    float* outV = out;                                  // N*128 f32
    float* outE = out + (size_t)N * 128;                // NE*128 f32  (doubles as P0)
    float* outI = outE + (size_t)NE * 128;              // NE f32

    char* ws = (char*)d_ws;
    int* Eidx = (int*)ws;
    size_t off = ((size_t)NE * 4 + 255) & ~(size_t)255;
    float* Xa = (float*)(ws + off);
    off += (((size_t)N * NAT * 3 * 4) + 255) & ~(size_t)255;
    unsigned short* Wt2 = (unsigned short*)(ws + off);  // WT2N*8 bf16 = 811008 B
    off += ((size_t)WT2N * 8 * 2 + 255) & ~(size_t)255;
    float* P1 = (float*)(ws + off);                     // NE*128 f32 = 15.73 MB
    size_t offP2 = off + (((size_t)NE * 128 * 4 + 255) & ~(size_t)255);
    float* P2 = (float*)(ws + offP2);
    size_t need = offP2 + (size_t)NE * 128 * 4;
    bool split3 = (ws_size >= need);                    // deterministic gate

    int prepBlocks = (N + 255) / 256;
    int nodeBlocks = (N + 3) / 4;
    int frontBlocks = N + WT2_BLOCKS + prepBlocks + nodeBlocks;
    k_front<<<dim3(frontBlocks), dim3(256), 0, stream>>>(X, mask, Eidx, outI, Xa, edge_w, Wt2,
                                                         S, BB, node_w, node_b, node_g, node_lb, outV, N);
    if (split3) {
        k_edge3<<<dim3(((NE + EPB - 1) / EPB) * 3), dim3(64), 0, stream>>>(Xa, Eidx, Wt2, outE, P1, P2, N);
        k_lnred3<<<dim3(NE), dim3(64), 0, stream>>>(outE, P1, P2, edge_b, edge_g, edge_lb, outE);
    } else {
        k_edge1<<<dim3((NE + EPB - 1) / EPB), dim3(64), 0, stream>>>(Xa, Eidx, Wt2, edge_b, edge_g, edge_lb, outE, N);
    }
}

// Round 20
// 133.631 us; speedup vs baseline: 1.4438x; 1.4054x over previous
//
#include <hip/hip_runtime.h>
#include <hip/hip_bf16.h>

#define TOPK 30
#define NAT 14
#define EDGE_IN 3152   // 16 PE + 14*14*16 RBF
#define NCHUNK 99      // K chunks of 32 (3168 padded)
#define EPB 32         // edges per k_edge block (one wave, M=32)
#define KSPLIT 50      // ks=0: [0,50), ks=1: [50,99)
#define WT2N (NCHUNK * 8 * 64)          // 50688 fragment slices
#define WT2_BLOCKS ((WT2N + 255) / 256) // 198

typedef __attribute__((ext_vector_type(8))) short bf16x8;
typedef __attribute__((ext_vector_type(4))) float f32x4;

__device__ __forceinline__ unsigned short f2bf(float f) {
    union { float f; unsigned u; } v; v.f = f;
    unsigned r = v.u + 0x7FFF + ((v.u >> 16) & 1);   // RNE
    return (unsigned short)(r >> 16);
}
__device__ __forceinline__ float bf2f(unsigned short h) {
    union { unsigned u; float f; } v; v.u = ((unsigned)h) << 16;
    return v.f;
}
__device__ __forceinline__ short cvtbf(float f) {    // proven scalar path (116 VGPR in r13/r14)
    __hip_bfloat16 h = __float2bfloat16(f);
    return *reinterpret_cast<short*>(&h);
}

// ---------------- merged front: KNN blocks [0,N) + misc (Wt2/prep/node) after ----------------
__global__ __launch_bounds__(256) void k_front(const float* __restrict__ X, const float* __restrict__ mask,
                                               int* __restrict__ Eidx, float* __restrict__ outI,
                                               float* __restrict__ Xa,
                                               const float* __restrict__ EW, unsigned short* __restrict__ Wt2,
                                               const int* __restrict__ S, const float* __restrict__ BB,
                                               const float* __restrict__ NW, const float* __restrict__ nb,
                                               const float* __restrict__ ng, const float* __restrict__ nbe,
                                               float* __restrict__ outV, int N) {
    __shared__ double sMax[4];
    __shared__ double sCd[128];
    __shared__ int    sCj[128];
    int b = blockIdx.x;
    if (b < N) {
        // ---- exact stable KNN in f64, two-phase register top-k (proven r13) ----
        int i = b, t = threadIdx.x;
        int w = t >> 6, ln = t & 63;
        double mi = (double)mask[i];
        double xx = (double)X[((size_t)i * NAT + 1) * 3 + 0];
        double xy = (double)X[((size_t)i * NAT + 1) * 3 + 1];
        double xz = (double)X[((size_t)i * NAT + 1) * 3 + 2];
        double dv[4], m2v[4];
        double lmax = -1.0;
#pragma unroll
        for (int k = 0; k < 4; k++) {
            int j = w * 256 + ln + 64 * k;
            if (j < N) {
                double dx = xx - (double)X[((size_t)j * NAT + 1) * 3 + 0];
                double dy = xy - (double)X[((size_t)j * NAT + 1) * 3 + 1];
                double dz = xz - (double)X[((size_t)j * NAT + 1) * 3 + 2];
                double sq = ((dx * dx + dy * dy) + dz * dz) + 1e-6;
                double m2 = mi * (double)mask[j];
                double d = m2 * sqrt(sq);
                dv[k] = d; m2v[k] = m2;
                lmax = fmax(lmax, d);
            } else { dv[k] = 1e300; m2v[k] = 1.0; }
        }
#pragma unroll
        for (int m = 32; m; m >>= 1) lmax = fmax(lmax, __shfl_xor(lmax, m));
        if (ln == 0) sMax[w] = lmax;
        __syncthreads();
        double Dmax = fmax(fmax(sMax[0], sMax[1]), fmax(sMax[2], sMax[3]));
#pragma unroll
        for (int k = 0; k < 4; k++) {
            int j = w * 256 + ln + 64 * k;
            if (j < N) dv[k] = dv[k] + 2.0 * (1.0 - m2v[k]) * Dmax;
        }
        for (int s = 0; s < TOPK; s++) {
            double bd = dv[0]; int bj = w * 256 + ln;
            if (dv[1] < bd) { bd = dv[1]; bj = w * 256 + ln + 64; }
            if (dv[2] < bd) { bd = dv[2]; bj = w * 256 + ln + 128; }
            if (dv[3] < bd) { bd = dv[3]; bj = w * 256 + ln + 192; }
#pragma unroll
            for (int m = 32; m; m >>= 1) {
                double od = __shfl_xor(bd, m);
                int oj = __shfl_xor(bj, m);
                if (od < bd || (od == bd && oj < bj)) { bd = od; bj = oj; }
            }
            if (ln == 0) { sCd[w * TOPK + s] = bd; sCj[w * TOPK + s] = bj; }
            int rel = bj - w * 256 - ln;
            if (rel == 0)        dv[0] = 1e300;
            else if (rel == 64)  dv[1] = 1e300;
            else if (rel == 128) dv[2] = 1e300;
            else if (rel == 192) dv[3] = 1e300;
        }
        __syncthreads();
        if (w == 0) {
            double c0 = (ln < 4 * TOPK) ? sCd[ln] : 1e300;
            int    j0 = (ln < 4 * TOPK) ? sCj[ln] : 0x7FFFFFFF;
            int l1 = ln + 64;
            double c1 = (l1 < 4 * TOPK) ? sCd[l1] : 1e300;
            int    j1 = (l1 < 4 * TOPK) ? sCj[l1] : 0x7FFFFFFF;
            for (int s = 0; s < TOPK; s++) {
                double bd = c0; int bj = j0;
                if (c1 < bd || (c1 == bd && j1 < bj)) { bd = c1; bj = j1; }
#pragma unroll
                for (int m = 32; m; m >>= 1) {
                    double od = __shfl_xor(bd, m);
                    int oj = __shfl_xor(bj, m);
                    if (od < bd || (od == bd && oj < bj)) { bd = od; bj = oj; }
                }
                if (ln == 0) {
                    Eidx[(size_t)i * TOPK + s] = bj;
                    outI[(size_t)i * TOPK + s] = (float)bj;
                }
                if (j0 == bj) c0 = 1e300;
                if (j1 == bj) c1 = 1e300;
            }
        }
        return;
    }
    b -= N;
    if (b < WT2_BLOCKS) {
        int gid = b * 256 + threadIdx.x;
        if (gid >= WT2N) return;
        int ln = gid & 63;
        int kcf = gid >> 6;
        int kc = kcf >> 3, f = kcf & 7;
        int c = f * 16 + (ln & 15);
        int k0 = kc * 32 + (ln >> 4) * 8;
        bf16x8 o;
#pragma unroll
        for (int e = 0; e < 8; e++) {
            int k = k0 + e;
            float v = (k < EDGE_IN) ? EW[(size_t)k * 128 + c] : 0.f;
            o[e] = (short)f2bf(v);
        }
        *reinterpret_cast<bf16x8*>(Wt2 + (size_t)gid * 8) = o;
        return;
    }
    b -= WT2_BLOCKS;
    int prepBlocks = (N + 255) / 256;
    if (b < prepBlocks) {
        int i = b * 256 + threadIdx.x;
        if (i >= N) return;
        const float* xi = X + (size_t)i * NAT * 3;
        float* xo = Xa + (size_t)i * NAT * 3;
        float Nx = xi[0], Ny = xi[1], Nz = xi[2];
        float Ax = xi[3], Ay = xi[4], Az = xi[5];
        float Cx = xi[6], Cy = xi[7], Cz = xi[8];
        float bx = Ax - Nx, by = Ay - Ny, bz = Az - Nz;
        float cx = Cx - Ax, cy = Cy - Ay, cz = Cz - Az;
        float ax = by * cz - bz * cy;
        float ay = bz * cx - bx * cz;
        float az = bx * cy - by * cx;
        float Cbx = -0.58273431f * ax + 0.56802827f * bx - 0.54067466f * cx + Ax;
        float Cby = -0.58273431f * ay + 0.56802827f * by - 0.54067466f * cy + Ay;
        float Cbz = -0.58273431f * az + 0.56802827f * bz - 0.54067466f * cz + Az;
#pragma unroll
        for (int a = 0; a < 4; a++) { xo[a*3] = xi[a*3]; xo[a*3+1] = xi[a*3+1]; xo[a*3+2] = xi[a*3+2]; }
        xo[12] = Cbx; xo[13] = Cby; xo[14] = Cbz;
#pragma unroll
        for (int a = 5; a < 14; a++) { xo[a*3] = xi[a*3]; xo[a*3+1] = xi[a*3+1]; xo[a*3+2] = xi[a*3+2]; }
        return;
    }
    b -= prepBlocks;
    int i = b * 4 + (threadIdx.x >> 6);
    if (i >= N) return;
    int t = threadIdx.x & 63;
    int s = S[i];
    float b0 = BB[i*6], b1 = BB[i*6+1], b2 = BB[i*6+2], b3 = BB[i*6+3], b4 = BB[i*6+4], b5 = BB[i*6+5];
    int t2 = t + 64;
    float x0 = NW[(size_t)s*128 + t] + nb[t]
             + b0*NW[21*128+t] + b1*NW[22*128+t] + b2*NW[23*128+t]
             + b3*NW[24*128+t] + b4*NW[25*128+t] + b5*NW[26*128+t];
    float x1 = NW[(size_t)s*128 + t2] + nb[t2]
             + b0*NW[21*128+t2] + b1*NW[22*128+t2] + b2*NW[23*128+t2]
             + b3*NW[24*128+t2] + b4*NW[25*128+t2] + b5*NW[26*128+t2];
    float sum = x0 + x1;
#pragma unroll
    for (int m = 32; m; m >>= 1) sum += __shfl_xor(sum, m);
    float mean = sum * (1.f / 128.f);
    float d0 = x0 - mean, d1 = x1 - mean;
    float vs = d0*d0 + d1*d1;
#pragma unroll
    for (int m = 32; m; m >>= 1) vs += __shfl_xor(vs, m);
    float inv = 1.f / sqrtf(vs * (1.f / 128.f) + 1e-5f);
    outV[(size_t)i*128 + t]  = d0 * inv * ng[t]  + nbe[t];
    outV[(size_t)i*128 + t2] = d1 * inv * ng[t2] + nbe[t2];
}

// ---------------- A-fragment generator: r13/r14-proven scalar path, D passed in ----------------
__device__ __forceinline__ bf16x8 genA(int kb, float dpe, unsigned short du) {
    const float FR[8] = {1.0f, 0.31622776601683794f, 0.1f, 0.03162277660168379f,
                         0.01f, 0.0031622776601683794f, 0.001f, 0.00031622776601683794f};
    const float CS = 0.96089796f;   // 0.8*sqrt(log2 e)
    const float CJ = 1.28119728f;   // (4/3)*CS
    bf16x8 a;
    if (kb < 16) {
#pragma unroll
        for (int jj = 0; jj < 8; jj++) {
            float ang = dpe * FR[jj];
            a[jj] = cvtbf((kb == 0) ? cosf(ang) : sinf(ang));
        }
    } else if (kb >= EDGE_IN) {
#pragma unroll
        for (int jj = 0; jj < 8; jj++) a[jj] = 0;
    } else {
        float D = bf2f(du);
        float bse = (float)((kb - 16) & 15);
        float Dss = D * CS - bse * CJ;
#pragma unroll
        for (int jj = 0; jj < 8; jj++) {
            float u = Dss - (float)jj * CJ;
            a[jj] = cvtbf(__builtin_amdgcn_exp2f(-u * u));
        }
    }
    return a;
}

__device__ __forceinline__ int idxD(int kc, int koff) {
    int idx = 2 * kc + (koff >> 1) - 1;
    return idx < 0 ? 0 : (idx > 195 ? 195 : idx);
}

// ---------------- fused edge features + bf16 MFMA GEMM (K-split-2, r14-verbatim) ----------------
// 1920 independent one-wave blocks: eb = bid>>1 (32 edges), ks = bid&1
// (chunks [0,50) or [50,99)). Monolithic body (116 VGPR in r14 — keep it that
// way; the function-factored version compiled to 132 and crossed the 128 cliff).
__global__ __launch_bounds__(64) void k_edge(const float* __restrict__ Xa, const int* __restrict__ Eidx,
                                             const unsigned short* __restrict__ Wt2,
                                             float* __restrict__ P0, float* __restrict__ P1, int N) {
    __shared__ unsigned short sDh[EPB * 200];            // bf16 D table, 12.8 KB
    __shared__ float sDpe[EPB];
    const int NE = N * TOPK;
    int t = threadIdx.x;                 // 0..63, one wave
    int eb = blockIdx.x >> 1, ks = blockIdx.x & 1;
    int geBase = eb * EPB;
    int kc0 = ks ? KSPLIT : 0;
    int kcEnd = ks ? NCHUNK : KSPLIT;
    float* Pdst = ks ? P1 : P0;

    const unsigned short* gB = Wt2 + (size_t)t * 8;      // lane fragment base

    // prologue: issue first B chunk so it flies under the D-table build
    bf16x8 bA[8], bB[8];
#pragma unroll
    for (int f = 0; f < 8; f++)
        bA[f] = *reinterpret_cast<const bf16x8*>(gB + ((size_t)kc0 * 8 + f) * 512);

    // D-table build: 2 threads per edge, 98 pair-distances each
    {
        int le = t >> 1, q = t & 1;
        int ge = geBase + le; if (ge >= NE) ge = NE - 1;
        int i = ge / TOPK;
        int j = Eidx[ge];
        if (q == 0) sDpe[le] = (float)j - (float)i;
        const float* Xi = Xa + (size_t)i * NAT * 3;
        const float* Xj = Xa + (size_t)j * NAT * 3;
        for (int p = q; p < 196; p += 2) {
            int a = p / 14, b = p - 14 * a;
            float dx = Xi[a*3+0] - Xj[b*3+0];
            float dy = Xi[a*3+1] - Xj[b*3+1];
            float dz = Xi[a*3+2] - Xj[b*3+2];
            sDh[le * 200 + p] = f2bf(sqrtf(dx*dx + dy*dy + dz*dz + 1e-6f));
        }
    }
    asm volatile("s_waitcnt lgkmcnt(0)" ::: "memory");   // single wave: our ds_writes done

    int lrow = t & 15, koff = t >> 4;
    const unsigned short* sDrow0 = sDh + (size_t)lrow * 200;
    const unsigned short* sDrow1 = sDh + (size_t)(lrow + 16) * 200;
    float dpe0 = sDpe[lrow];
    float dpe1 = sDpe[lrow + 16];

    f32x4 acc0[8], acc1[8];
#pragma unroll
    for (int f = 0; f < 8; f++) { acc0[f] = (f32x4){0.f,0.f,0.f,0.f}; acc1[f] = (f32x4){0.f,0.f,0.f,0.f}; }

    // D pipeline prologue: chunks kc0, kc0+1, kc0+2
    int i0 = idxD(kc0, koff), i1 = idxD(kc0 + 1, koff), i2 = idxD(kc0 + 2, koff);
    unsigned short p0a = sDrow0[i0], p0b = sDrow1[i0];
    unsigned short p1a = sDrow0[i1], p1b = sDrow1[i1];
    unsigned short p2a = sDrow0[i2], p2b = sDrow1[i2];

    bf16x8 a0c = genA(kc0 * 32 + koff * 8, dpe0, p0a);
    bf16x8 a1c = genA(kc0 * 32 + koff * 8, dpe1, p0b);

    for (int kc = kc0; kc < kcEnd; kc += 2) {
        int i3 = idxD(kc + 3, koff);
        unsigned short p3a = sDrow0[i3], p3b = sDrow1[i3];
        bf16x8 a0n, a1n;
        if (kc + 1 < kcEnd) {
#pragma unroll
            for (int f = 0; f < 8; f++)
                bB[f] = *reinterpret_cast<const bf16x8*>(gB + ((size_t)(kc + 1) * 8 + f) * 512);
            int kb = (kc + 1) * 32 + koff * 8;
            a0n = genA(kb, dpe0, p1a);
            a1n = genA(kb, dpe1, p1b);
        }
#pragma unroll
        for (int f = 0; f < 8; f++) {
            acc0[f] = __builtin_amdgcn_mfma_f32_16x16x32_bf16(a0c, bA[f], acc0[f], 0, 0, 0);
            acc1[f] = __builtin_amdgcn_mfma_f32_16x16x32_bf16(a1c, bA[f], acc1[f], 0, 0, 0);
        }
        int i4 = idxD(kc + 4, koff);
        unsigned short p4a = sDrow0[i4], p4b = sDrow1[i4];
        if (kc + 2 < kcEnd) {
#pragma unroll
            for (int f = 0; f < 8; f++)
                bA[f] = *reinterpret_cast<const bf16x8*>(gB + ((size_t)(kc + 2) * 8 + f) * 512);
            int kb = (kc + 2) * 32 + koff * 8;
            a0c = genA(kb, dpe0, p2a);
            a1c = genA(kb, dpe1, p2b);
        }
        if (kc + 1 < kcEnd) {
#pragma unroll
            for (int f = 0; f < 8; f++) {
                acc0[f] = __builtin_amdgcn_mfma_f32_16x16x32_bf16(a0n, bB[f], acc0[f], 0, 0, 0);
                acc1[f] = __builtin_amdgcn_mfma_f32_16x16x32_bf16(a1n, bB[f], acc1[f], 0, 0, 0);
            }
        }
        p1a = p3a; p1b = p3b;
        p2a = p4a; p2b = p4b;
    }

    // write raw f32 partial (uniform store body; no bias/LN here)
#pragma unroll
    for (int g2 = 0; g2 < 2; g2++) {
#pragma unroll
        for (int r = 0; r < 4; r++) {
            int row = geBase + g2 * 16 + koff * 4 + r;
            if (row < NE) {
                float* po = Pdst + (size_t)row * 128 + lrow;
#pragma unroll
                for (int f = 0; f < 8; f++) po[f * 16] = (g2 ? acc1[f][r] : acc0[f][r]);
            }
        }
    }
}

// ---------------- reduce partials + bias + LN (one wave per row, r14-verbatim) ----------------
__global__ __launch_bounds__(64) void k_lnred(const float* __restrict__ P0, const float* __restrict__ P1,
                                              const float* __restrict__ eb, const float* __restrict__ gg,
                                              const float* __restrict__ bb, float* __restrict__ outE) {
    int row = blockIdx.x, t = threadIdx.x;
    int c0 = t, c1 = t + 64;
    size_t base = (size_t)row * 128;
    float x0 = P0[base + c0] + P1[base + c0] + eb[c0];
    float x1 = P0[base + c1] + P1[base + c1] + eb[c1];
    float sum = x0 + x1;
#pragma unroll
    for (int m = 32; m; m >>= 1) sum += __shfl_xor(sum, m);
    float mean = sum * (1.f / 128.f);
    float d0 = x0 - mean, d1 = x1 - mean;
    float vs = d0*d0 + d1*d1;
#pragma unroll
    for (int m = 32; m; m >>= 1) vs += __shfl_xor(vs, m);
    float inv = 1.f / sqrtf(vs * (1.f / 128.f) + 1e-5f);
    outE[base + c0] = d0 * inv * gg[c0] + bb[c0];
    outE[base + c1] = d1 * inv * gg[c1] + bb[c1];
}

extern "C" void kernel_launch(void* const* d_in, const int* in_sizes, int n_in,
                              void* d_out, int out_size, void* d_ws, size_t ws_size,
                              hipStream_t stream) {
    const float* X       = (const float*)d_in[0];
    const int*   S       = (const int*)d_in[1];
    const float* BB      = (const float*)d_in[2];
    const float* mask    = (const float*)d_in[3];
    const float* node_w  = (const float*)d_in[4];
    const float* node_b  = (const float*)d_in[5];
    const float* node_g  = (const float*)d_in[6];
    const float* node_lb = (const float*)d_in[7];
    const float* edge_w  = (const float*)d_in[8];
    const float* edge_b  = (const float*)d_in[9];
    const float* edge_g  = (const float*)d_in[10];
    const float* edge_lb = (const float*)d_in[11];
    int N  = in_sizes[1];       // 1024
    int NE = N * TOPK;

    float* out  = (float*)d_out;
    float* outV = out;                                  // N*128 f32
    float* outE = out + (size_t)N * 128;                // NE*128 f32  (doubles as P0)
    float* outI = outE + (size_t)NE * 128;              // NE f32

    char* ws = (char*)d_ws;
    int* Eidx = (int*)ws;
    size_t off = ((size_t)NE * 4 + 255) & ~(size_t)255;
    float* Xa = (float*)(ws + off);
    off += (((size_t)N * NAT * 3 * 4) + 255) & ~(size_t)255;
    unsigned short* Wt2 = (unsigned short*)(ws + off);  // WT2N*8 bf16 = 811008 B
    off += ((size_t)WT2N * 8 * 2 + 255) & ~(size_t)255;
    float* P1 = (float*)(ws + off);                     // NE*128 f32 = 15.73 MB partial

    int prepBlocks = (N + 255) / 256;
    int nodeBlocks = (N + 3) / 4;
    int frontBlocks = N + WT2_BLOCKS + prepBlocks + nodeBlocks;
    k_front<<<dim3(frontBlocks), dim3(256), 0, stream>>>(X, mask, Eidx, outI, Xa, edge_w, Wt2,
                                                         S, BB, node_w, node_b, node_g, node_lb, outV, N);
    k_edge<<<dim3(((NE + EPB - 1) / EPB) * 2), dim3(64), 0, stream>>>(Xa, Eidx, Wt2, outE, P1, N);
    k_lnred<<<dim3(NE), dim3(64), 0, stream>>>(outE, P1, edge_b, edge_g, edge_lb, outE);
}